// Round 4
// baseline (84.431 us; speedup 1.0000x reference)
//
#include <hip/hip_runtime.h>
#include <hip/hip_bf16.h>
#include <math.h>

// ---------- types ----------
typedef __attribute__((ext_vector_type(8))) short s8v;   // 8 bf16 (4 VGPRs) - MFMA A/B frag
typedef __attribute__((ext_vector_type(4))) short s4v;   // 4 bf16 (8B store)
typedef __attribute__((ext_vector_type(4))) float f4v;   // 4 f32 - MFMA C/D frag

#define HW   512
#define NIMG 24
#define MAT  (HW*HW)   // 262144

// round-to-nearest-even f32 -> bf16 bits
__device__ __forceinline__ unsigned short f2bf(float f) {
  unsigned u = __builtin_bit_cast(unsigned, f);
  u += 0x7fffu + ((u >> 16) & 1u);
  return (unsigned short)(u >> 16);
}
__device__ __forceinline__ float bf2f(unsigned short b) {
  return __builtin_bit_cast(float, (unsigned)b << 16);
}

__device__ __forceinline__ int band_of(int s) {
  return s == 0 ? 30 : (s == 1 ? 160 : 500);   // 2*scale
}
// K-block range [kblo, kbhi) of nonzero G_s band for m-tile [m0, m0+128)
__device__ __forceinline__ int kblo_f(int m0, int s) {
  int lo = m0 - band_of(s); if (lo < 0) lo = 0; return lo >> 6;
}
__device__ __forceinline__ int kbhi_f(int m0, int s) {
  int hi = m0 + 128 + band_of(s); if (hi > HW) hi = HW; return (hi + 63) >> 6;
}

// fast log1p for z >= 0: v_log_f32 (log2) * ln2, ~1 ulp on 1+z
__device__ __forceinline__ float fast_log1p(float z) {
  float a = 1.0f + z;
  float l;
#if __has_builtin(__builtin_amdgcn_logf)
  l = __builtin_amdgcn_logf(a);
#else
  asm("v_log_f32 %0, %1" : "=v"(l) : "v"(a));
#endif
  return l * 0.69314718055994531f;
}

// ---------- prep: blocks [0,768) generate G (bf16); [768,768+6144) convert x->Xb
// (+ optionally out = log1p(x) for the fallback path) ----------
#define NG_BLOCKS 768            // 3*MAT / (256*4)
#define NX_BLOCKS 6144           // NIMG*MAT / (256*4)
__global__ __launch_bounds__(256) void prep_kernel(
    const float* __restrict__ x,
    unsigned short* __restrict__ G,
    unsigned short* __restrict__ Xb,
    float* __restrict__ out, int writeOut,
    float i2s0, float i2s1, float i2s2,
    float n0, float n1, float n2) {
  int b = blockIdx.x;
  if (b < NG_BLOCKS) {
    int gid = b * 256 + threadIdx.x;     // one per 4 consecutive j
    int s   = gid >> 16;                 // 65536 quads per scale
    int rem = gid & 65535;
    int i = rem >> 7, j0 = (rem & 127) << 2;
    float i2s = (s == 0) ? i2s0 : (s == 1 ? i2s1 : i2s2);
    float nrm = (s == 0) ? n0  : (s == 1 ? n1  : n2);
    int band = band_of(s);
    s4v o;
    #pragma unroll
    for (int e = 0; e < 4; ++e) {
      int d = j0 + e - i;
      int ad = d < 0 ? -d : d;
      float val = 0.f;
      if (ad <= band) val = expf(-(float)(d * d) * i2s) * nrm;
      o[e] = (short)f2bf(val);
    }
    *(s4v*)(G + (size_t)gid * 4) = o;
  } else {
    int i = (b - NG_BLOCKS) * 256 + threadIdx.x;   // 4 elements each
    f4v v = *(const f4v*)(x + (size_t)i * 4);
    s4v bv;
    #pragma unroll
    for (int e = 0; e < 4; ++e) bv[e] = (short)f2bf(v[e]);
    *(s4v*)(Xb + (size_t)i * 4) = bv;
    if (writeOut) {
      f4v o;
      #pragma unroll
      for (int e = 0; e < 4; ++e) o[e] = fast_log1p(v[e]);
      *(f4v*)(out + (size_t)i * 4) = o;
    }
  }
}

// ---------- swizzled LDS staging (proven: 0 bank conflicts) ----------
// LDS tile: NROWS x 64 bf16 (128B/row). 16B chunk `ch` of row r lives at
// byte r*128 + (ch ^ (r&7))*16. global_load_lds writes LINEARLY, so the
// *source* address is pre-permuted instead (both-sides-or-neither).
template<int NROWS>
__device__ __forceinline__ void stage_tile(const unsigned short* __restrict__ src,
                                           short* lds, int w, int l) {
  #pragma unroll
  for (int c = 0; c < NROWS / 32; ++c) {
    int cid = c * 4 + w;                   // 1KB chunk-groups
    int chunk = cid * 64 + l;              // 16B chunk id within tile
    int row = chunk >> 3, ch = chunk & 7;
    const char* g = (const char*)src + row * (HW * 2) + ((ch ^ (row & 7)) << 4);
    __builtin_amdgcn_global_load_lds(
        (const __attribute__((address_space(1))) void*)g,
        (__attribute__((address_space(3))) void*)(lds + (cid << 9)),
        16, 0, 0);
  }
}

__device__ __forceinline__ s8v lds_frag(const short* base, int row, int chunk) {
  return *(const s8v*)((const char*)base + row * 128 + ((chunk ^ (row & 7)) << 4));
}

// ---------- MFMA compute for one BK=64 step, BM=128 x BN=64, 4 waves ----------
__device__ __forceinline__ void compute_bk64(const short* Ab, const short* Bb,
                                             int wr, int wc, int lrow, int lq,
                                             f4v (&acc)[4][2]) {
  s8v af[2][4], bf[2][2];
  #pragma unroll
  for (int kk = 0; kk < 2; ++kk) {
    int chunk = (kk << 2) + lq;
    #pragma unroll
    for (int mi = 0; mi < 4; ++mi)
      af[kk][mi] = lds_frag(Ab, wr + mi * 16 + lrow, chunk);
    #pragma unroll
    for (int ni = 0; ni < 2; ++ni)
      bf[kk][ni] = lds_frag(Bb, wc + ni * 16 + lrow, chunk);
  }
  __builtin_amdgcn_s_setprio(1);
  #pragma unroll
  for (int kk = 0; kk < 2; ++kk)
    #pragma unroll
    for (int mi = 0; mi < 4; ++mi)
      #pragma unroll
      for (int ni = 0; ni < 2; ++ni)
        acc[mi][ni] = __builtin_amdgcn_mfma_f32_16x16x32_bf16(af[kk][mi], bf[kk][ni], acc[mi][ni], 0, 0, 0);
  __builtin_amdgcn_s_setprio(0);
}

// Phase boundary helpers (T3-min 2-phase, counted vmcnt — never 0 mid-loop)
__device__ __forceinline__ void open_phase_wait6() {
  asm volatile("s_waitcnt vmcnt(6)" ::: "memory");
  __builtin_amdgcn_s_barrier();
  __builtin_amdgcn_sched_barrier(0);
}
__device__ __forceinline__ void open_phase_wait0() {
  asm volatile("s_waitcnt vmcnt(0)" ::: "memory");
  __builtin_amdgcn_s_barrier();
  __builtin_amdgcn_sched_barrier(0);
}
__device__ __forceinline__ void close_phase() {
  __builtin_amdgcn_sched_barrier(0);
  __builtin_amdgcn_s_barrier();
}

// ---------- pass 1 (fused NS scales): Ut[sl][img][m][n] = bf16(sum_k G_s[m][k]*Xb[img][n][k]) ----------
// BM=128, BN=64; grid = NIMG*32 = 768 (3 blocks/CU, all resident); dbuf LDS 48KB.
template<int NS>
__global__ __launch_bounds__(256) void pass1_kernel(
    const unsigned short* __restrict__ G,
    const unsigned short* __restrict__ Xb,
    unsigned short* __restrict__ Ut,
    int scale0) {
  __shared__ __align__(16) short As[2][128 * 64];
  __shared__ __align__(16) short Bs[2][64 * 64];

  int bid  = blockIdx.x;
  int tile = bid & 31;            // 4 m-tiles x 8 n-tiles
  int img  = bid >> 5;
  int m0 = (tile >> 3) * 128;
  int n0 = (tile & 7) * 64;

  int t = threadIdx.x;
  int lane = t & 63;
  int w  = t >> 6;
  int wr = (w >> 1) * 64;
  int wc = (w & 1) * 32;
  int lrow = lane & 15;
  int lq   = lane >> 4;

  const unsigned short* Bbase = Xb + img * MAT + n0 * HW;

  // stage cursor (block-uniform control flow)
  int sl_s = 0, kb_s = kblo_f(m0, scale0);
  stage_tile<128>(G + (scale0 + sl_s) * MAT + m0 * HW + (kb_s << 6), As[0], w, lane);
  stage_tile<64>(Bbase + (kb_s << 6), Bs[0], w, lane);
  if (++kb_s == kbhi_f(m0, scale0 + sl_s)) { ++sl_s; if (sl_s < NS) kb_s = kblo_f(m0, scale0 + sl_s); }
  int cur = 0;

  for (int sl = 0; sl < NS; ++sl) {
    f4v acc[4][2];
    #pragma unroll
    for (int mi = 0; mi < 4; ++mi)
      #pragma unroll
      for (int ni = 0; ni < 2; ++ni)
        #pragma unroll
        for (int r = 0; r < 4; ++r) acc[mi][ni][r] = 0.f;

    int klo = kblo_f(m0, scale0 + sl), khi = kbhi_f(m0, scale0 + sl);
    for (int kb = klo; kb < khi; ++kb) {
      if (sl_s < NS) {
        stage_tile<128>(G + (scale0 + sl_s) * MAT + m0 * HW + (kb_s << 6), As[cur ^ 1], w, lane);
        stage_tile<64>(Bbase + (kb_s << 6), Bs[cur ^ 1], w, lane);
        if (++kb_s == kbhi_f(m0, scale0 + sl_s)) { ++sl_s; if (sl_s < NS) kb_s = kblo_f(m0, scale0 + sl_s); }
        open_phase_wait6();
      } else {
        open_phase_wait0();
      }
      compute_bk64(As[cur], Bs[cur], wr, wc, lrow, lq, acc);
      close_phase();
      cur ^= 1;
    }

    unsigned short* O = Ut + (sl * NIMG + img) * MAT;
    #pragma unroll
    for (int mi = 0; mi < 4; ++mi)
      #pragma unroll
      for (int r = 0; r < 4; ++r) {
        int m = m0 + wr + mi * 16 + lq * 4 + r;
        #pragma unroll
        for (int ni = 0; ni < 2; ++ni) {
          int n = n0 + wc + ni * 16 + lrow;
          O[m * HW + n] = f2bf(acc[mi][ni][r]);
        }
      }
  }
}

// ---------- pass 2 (fused NS scales, no atomics) ----------
// Z_s[m][n] = sum_k G_s[m][k]*Ut[sl][img][n][k]; suml = sum_s log1p(Z_s)
// ACCUM=0: out = log1p(xb) - suml/3    ACCUM=1: out -= suml/3
template<int NS, int ACCUM>
__global__ __launch_bounds__(256) void pass2_kernel(
    const unsigned short* __restrict__ G,
    const unsigned short* __restrict__ Ut,
    const unsigned short* __restrict__ Xb,
    float* __restrict__ out,
    int scale0) {
  __shared__ __align__(16) short As[2][128 * 64];
  __shared__ __align__(16) short Bs[2][64 * 64];

  int bid  = blockIdx.x;
  int tile = bid & 31;
  int img  = bid >> 5;
  int m0 = (tile >> 3) * 128;
  int n0 = (tile & 7) * 64;

  int t = threadIdx.x;
  int lane = t & 63;
  int w  = t >> 6;
  int wr = (w >> 1) * 64;
  int wc = (w & 1) * 32;
  int lrow = lane & 15;
  int lq   = lane >> 4;

  int sl_s = 0, kb_s = kblo_f(m0, scale0);
  stage_tile<128>(G + (scale0 + sl_s) * MAT + m0 * HW + (kb_s << 6), As[0], w, lane);
  stage_tile<64>(Ut + (sl_s * NIMG + img) * MAT + n0 * HW + (kb_s << 6), Bs[0], w, lane);
  if (++kb_s == kbhi_f(m0, scale0 + sl_s)) { ++sl_s; if (sl_s < NS) kb_s = kblo_f(m0, scale0 + sl_s); }
  int cur = 0;

  float suml[4][2][4];
  #pragma unroll
  for (int mi = 0; mi < 4; ++mi)
    #pragma unroll
    for (int ni = 0; ni < 2; ++ni)
      #pragma unroll
      for (int r = 0; r < 4; ++r) suml[mi][ni][r] = 0.f;

  for (int sl = 0; sl < NS; ++sl) {
    f4v acc[4][2];
    #pragma unroll
    for (int mi = 0; mi < 4; ++mi)
      #pragma unroll
      for (int ni = 0; ni < 2; ++ni)
        #pragma unroll
        for (int r = 0; r < 4; ++r) acc[mi][ni][r] = 0.f;

    int klo = kblo_f(m0, scale0 + sl), khi = kbhi_f(m0, scale0 + sl);
    for (int kb = klo; kb < khi; ++kb) {
      if (sl_s < NS) {
        stage_tile<128>(G + (scale0 + sl_s) * MAT + m0 * HW + (kb_s << 6), As[cur ^ 1], w, lane);
        stage_tile<64>(Ut + (sl_s * NIMG + img) * MAT + n0 * HW + (kb_s << 6), Bs[cur ^ 1], w, lane);
        if (++kb_s == kbhi_f(m0, scale0 + sl_s)) { ++sl_s; if (sl_s < NS) kb_s = kblo_f(m0, scale0 + sl_s); }
        open_phase_wait6();
      } else {
        open_phase_wait0();
      }
      compute_bk64(As[cur], Bs[cur], wr, wc, lrow, lq, acc);
      close_phase();
      cur ^= 1;
    }

    #pragma unroll
    for (int mi = 0; mi < 4; ++mi)
      #pragma unroll
      for (int ni = 0; ni < 2; ++ni)
        #pragma unroll
        for (int r = 0; r < 4; ++r)
          suml[mi][ni][r] += fast_log1p(acc[mi][ni][r]);
  }

  const unsigned short* xb = Xb + img * MAT;
  float* O = out + img * MAT;
  #pragma unroll
  for (int mi = 0; mi < 4; ++mi)
    #pragma unroll
    for (int r = 0; r < 4; ++r) {
      int m = m0 + wr + mi * 16 + lq * 4 + r;
      #pragma unroll
      for (int ni = 0; ni < 2; ++ni) {
        int n = n0 + wc + ni * 16 + lrow;
        int idx = m * HW + n;
        if (ACCUM) {
          O[idx] = O[idx] - suml[mi][ni][r] * (1.0f / 3.0f);
        } else {
          O[idx] = fast_log1p(bf2f(xb[idx])) - suml[mi][ni][r] * (1.0f / 3.0f);
        }
      }
    }
}

// ---------- host ----------
extern "C" void kernel_launch(void* const* d_in, const int* in_sizes, int n_in,
                              void* d_out, int out_size, void* d_ws, size_t ws_size,
                              hipStream_t stream) {
  (void)in_sizes; (void)n_in; (void)out_size;
  const float* x = (const float*)d_in[0];
  float* out = (float*)d_out;
  unsigned short* Gbuf = (unsigned short*)d_ws;

  static const int scales[3] = {15, 80, 250};
  float i2s[3], nrm[3];
  for (int si = 0; si < 3; ++si) {
    double s = (double)scales[si];
    double S = 0.0;
    for (int c = -2 * scales[si]; c <= 2 * scales[si]; ++c)
      S += exp(-(double)c * (double)c / (2.0 * s * s));
    i2s[si] = (float)(1.0 / (2.0 * s * s));
    nrm[si] = (float)(1.0 / S);
  }

  size_t need_main = (size_t)(3 + 3 * NIMG + NIMG) * MAT * 2;  // G + Ut(3 scales) + Xb
  if (ws_size >= need_main) {
    unsigned short* Ut = Gbuf + 3 * MAT;
    unsigned short* Xb = Ut + (size_t)3 * NIMG * MAT;
    prep_kernel<<<NG_BLOCKS + NX_BLOCKS, 256, 0, stream>>>(
        x, Gbuf, Xb, out, 0, i2s[0], i2s[1], i2s[2], nrm[0], nrm[1], nrm[2]);
    pass1_kernel<3><<<NIMG * 32, 256, 0, stream>>>(Gbuf, Xb, Ut, 0);
    pass2_kernel<3, 0><<<NIMG * 32, 256, 0, stream>>>(Gbuf, Ut, Xb, out, 0);
  } else {
    // fallback: per-scale, Ut holds one scale (G + Ut(1) + Xb = 26.7MB)
    unsigned short* Ut = Gbuf + 3 * MAT;
    unsigned short* Xb = Ut + (size_t)NIMG * MAT;
    prep_kernel<<<NG_BLOCKS + NX_BLOCKS, 256, 0, stream>>>(
        x, Gbuf, Xb, out, 1, i2s[0], i2s[1], i2s[2], nrm[0], nrm[1], nrm[2]);
    for (int s = 0; s < 3; ++s) {
      pass1_kernel<1><<<NIMG * 32, 256, 0, stream>>>(Gbuf, Xb, Ut, s);
      pass2_kernel<1, 1><<<NIMG * 32, 256, 0, stream>>>(Gbuf, Ut, Xb, out, s);
    }
  }
}

// Round 5
// 59.838 us; speedup vs baseline: 1.4110x; 1.4110x over previous
//
#include <hip/hip_runtime.h>
#include <hip/hip_bf16.h>
#include <math.h>

// ---------- types ----------
typedef __attribute__((ext_vector_type(8))) short s8v;   // 8 bf16 (4 VGPRs) - MFMA A/B frag
typedef __attribute__((ext_vector_type(4))) short s4v;   // 4 bf16 (8B store)
typedef __attribute__((ext_vector_type(4))) float f4v;   // 4 f32 - MFMA C/D frag

#define HW   512
#define NIMG 24
#define MAT  (HW*HW)   // 262144

// round-to-nearest-even f32 -> bf16 bits
__device__ __forceinline__ unsigned short f2bf(float f) {
  unsigned u = __builtin_bit_cast(unsigned, f);
  u += 0x7fffu + ((u >> 16) & 1u);
  return (unsigned short)(u >> 16);
}
__device__ __forceinline__ float bf2f(unsigned short b) {
  return __builtin_bit_cast(float, (unsigned)b << 16);
}

__device__ __forceinline__ int band_of(int s) {
  return s == 0 ? 30 : (s == 1 ? 160 : 500);   // 2*scale
}
// K-block range [kblo, kbhi) of nonzero G_s band for m-tile [m0, m0+128)
__device__ __forceinline__ int kblo_f(int m0, int s) {
  int lo = m0 - band_of(s); if (lo < 0) lo = 0; return lo >> 6;
}
__device__ __forceinline__ int kbhi_f(int m0, int s) {
  int hi = m0 + 128 + band_of(s); if (hi > HW) hi = HW; return (hi + 63) >> 6;
}

// fast log1p for z >= 0: v_log_f32 (log2) * ln2, ~1 ulp on 1+z
__device__ __forceinline__ float fast_log1p(float z) {
  float a = 1.0f + z;
  float l;
#if __has_builtin(__builtin_amdgcn_logf)
  l = __builtin_amdgcn_logf(a);
#else
  asm("v_log_f32 %0, %1" : "=v"(l) : "v"(a));
#endif
  return l * 0.69314718055994531f;
}

// ---------- prep: blocks [0,768) generate G (bf16); [768,768+6144) convert x->Xb
// (+ optionally out = log1p(x) for the fallback path) ----------
#define NG_BLOCKS 768            // 3*MAT / (256*4)
#define NX_BLOCKS 6144           // NIMG*MAT / (256*4)
__global__ __launch_bounds__(256) void prep_kernel(
    const float* __restrict__ x,
    unsigned short* __restrict__ G,
    unsigned short* __restrict__ Xb,
    float* __restrict__ out, int writeOut,
    float i2s0, float i2s1, float i2s2,
    float n0, float n1, float n2) {
  int b = blockIdx.x;
  if (b < NG_BLOCKS) {
    int gid = b * 256 + threadIdx.x;     // one per 4 consecutive j
    int s   = gid >> 16;                 // 65536 quads per scale
    int rem = gid & 65535;
    int i = rem >> 7, j0 = (rem & 127) << 2;
    float i2s = (s == 0) ? i2s0 : (s == 1 ? i2s1 : i2s2);
    float nrm = (s == 0) ? n0  : (s == 1 ? n1  : n2);
    int band = band_of(s);
    s4v o;
    #pragma unroll
    for (int e = 0; e < 4; ++e) {
      int d = j0 + e - i;
      int ad = d < 0 ? -d : d;
      float val = 0.f;
      if (ad <= band) val = expf(-(float)(d * d) * i2s) * nrm;
      o[e] = (short)f2bf(val);
    }
    *(s4v*)(G + (size_t)gid * 4) = o;
  } else {
    int i = (b - NG_BLOCKS) * 256 + threadIdx.x;   // 4 elements each
    f4v v = *(const f4v*)(x + (size_t)i * 4);
    s4v bv;
    #pragma unroll
    for (int e = 0; e < 4; ++e) bv[e] = (short)f2bf(v[e]);
    *(s4v*)(Xb + (size_t)i * 4) = bv;
    if (writeOut) {
      f4v o;
      #pragma unroll
      for (int e = 0; e < 4; ++e) o[e] = fast_log1p(v[e]);
      *(f4v*)(out + (size_t)i * 4) = o;
    }
  }
}

// ---------- swizzled LDS staging (proven: 0 bank conflicts) ----------
// LDS tile: NROWS x 64 bf16 (128B/row). 16B chunk `ch` of row r lives at
// byte r*128 + (ch ^ (r&7))*16. global_load_lds writes LINEARLY, so the
// *source* address is pre-permuted instead (both-sides-or-neither).
template<int NROWS>
__device__ __forceinline__ void stage_tile(const unsigned short* __restrict__ src,
                                           short* lds, int w, int l) {
  #pragma unroll
  for (int c = 0; c < NROWS / 32; ++c) {
    int cid = c * 4 + w;                   // 1KB chunk-groups
    int chunk = cid * 64 + l;              // 16B chunk id within tile
    int row = chunk >> 3, ch = chunk & 7;
    const char* g = (const char*)src + row * (HW * 2) + ((ch ^ (row & 7)) << 4);
    __builtin_amdgcn_global_load_lds(
        (const __attribute__((address_space(1))) void*)g,
        (__attribute__((address_space(3))) void*)(lds + (cid << 9)),
        16, 0, 0);
  }
}

__device__ __forceinline__ s8v lds_frag(const short* base, int row, int chunk) {
  return *(const s8v*)((const char*)base + row * 128 + ((chunk ^ (row & 7)) << 4));
}

// ---------- MFMA compute for one BK=64 step, BM=128 x BN=64, 4 waves ----------
__device__ __forceinline__ void compute_bk64(const short* Ab, const short* Bb,
                                             int wr, int wc, int lrow, int lq,
                                             f4v (&acc)[4][2]) {
  #pragma unroll
  for (int kk = 0; kk < 2; ++kk) {
    s8v af[4], bf[2];
    int chunk = (kk << 2) + lq;
    #pragma unroll
    for (int mi = 0; mi < 4; ++mi)
      af[mi] = lds_frag(Ab, wr + mi * 16 + lrow, chunk);
    #pragma unroll
    for (int ni = 0; ni < 2; ++ni)
      bf[ni] = lds_frag(Bb, wc + ni * 16 + lrow, chunk);
    #pragma unroll
    for (int mi = 0; mi < 4; ++mi)
      #pragma unroll
      for (int ni = 0; ni < 2; ++ni)
        acc[mi][ni] = __builtin_amdgcn_mfma_f32_16x16x32_bf16(af[mi], bf[ni], acc[mi][ni], 0, 0, 0);
  }
}

// ---------- pass 1 (fused NS scales): Ut[sl][img][m][n] = bf16(sum_k G_s[m][k]*Xb[img][n][k]) ----------
// BM=128, BN=64; grid = NIMG*32 = 768; dbuf LDS 48KB -> 3 blocks/CU.
// T3-minimum 2-phase: STAGE(next, buf^1); compute(buf); __syncthreads(); flip.
template<int NS>
__global__ __launch_bounds__(256) void pass1_kernel(
    const unsigned short* __restrict__ G,
    const unsigned short* __restrict__ Xb,
    unsigned short* __restrict__ Ut,
    int scale0) {
  __shared__ __align__(16) short As[2][128 * 64];
  __shared__ __align__(16) short Bs[2][64 * 64];

  int bid  = blockIdx.x;
  int tile = bid & 31;            // 4 m-tiles x 8 n-tiles
  int img  = bid >> 5;
  int m0 = (tile >> 3) * 128;
  int n0 = (tile & 7) * 64;

  int t = threadIdx.x;
  int lane = t & 63;
  int w  = t >> 6;
  int wr = (w >> 1) * 64;
  int wc = (w & 1) * 32;
  int lrow = lane & 15;
  int lq   = lane >> 4;

  const unsigned short* Bbase = Xb + img * MAT + n0 * HW;

  // stage cursor (block-uniform control flow), one tile ahead
  int sl_s = 0, kb_s = kblo_f(m0, scale0);
  stage_tile<128>(G + (scale0 + sl_s) * MAT + m0 * HW + (kb_s << 6), As[0], w, lane);
  stage_tile<64>(Bbase + (kb_s << 6), Bs[0], w, lane);
  if (++kb_s == kbhi_f(m0, scale0 + sl_s)) { ++sl_s; if (sl_s < NS) kb_s = kblo_f(m0, scale0 + sl_s); }
  __syncthreads();
  int cur = 0;

  for (int sl = 0; sl < NS; ++sl) {
    f4v acc[4][2];
    #pragma unroll
    for (int mi = 0; mi < 4; ++mi)
      #pragma unroll
      for (int ni = 0; ni < 2; ++ni)
        #pragma unroll
        for (int r = 0; r < 4; ++r) acc[mi][ni][r] = 0.f;

    int klo = kblo_f(m0, scale0 + sl), khi = kbhi_f(m0, scale0 + sl);
    for (int kb = klo; kb < khi; ++kb) {
      if (sl_s < NS) {     // issue next-tile loads BEFORE compute (latency hides under MFMA)
        stage_tile<128>(G + (scale0 + sl_s) * MAT + m0 * HW + (kb_s << 6), As[cur ^ 1], w, lane);
        stage_tile<64>(Bbase + (kb_s << 6), Bs[cur ^ 1], w, lane);
        if (++kb_s == kbhi_f(m0, scale0 + sl_s)) { ++sl_s; if (sl_s < NS) kb_s = kblo_f(m0, scale0 + sl_s); }
      }
      compute_bk64(As[cur], Bs[cur], wr, wc, lrow, lq, acc);
      __syncthreads();     // one vmcnt(0)+barrier per tile (T3-min recipe)
      cur ^= 1;
    }

    unsigned short* O = Ut + (sl * NIMG + img) * MAT;
    #pragma unroll
    for (int mi = 0; mi < 4; ++mi)
      #pragma unroll
      for (int r = 0; r < 4; ++r) {
        int m = m0 + wr + mi * 16 + lq * 4 + r;
        #pragma unroll
        for (int ni = 0; ni < 2; ++ni) {
          int n = n0 + wc + ni * 16 + lrow;
          O[m * HW + n] = f2bf(acc[mi][ni][r]);
        }
      }
  }
}

// ---------- pass 2 (fused NS scales, no atomics) ----------
// Z_s[m][n] = sum_k G_s[m][k]*Ut[sl][img][n][k]; suml = sum_s log1p(Z_s)
// ACCUM=0: out = log1p(xb) - suml/3    ACCUM=1: out -= suml/3
template<int NS, int ACCUM>
__global__ __launch_bounds__(256) void pass2_kernel(
    const unsigned short* __restrict__ G,
    const unsigned short* __restrict__ Ut,
    const unsigned short* __restrict__ Xb,
    float* __restrict__ out,
    int scale0) {
  __shared__ __align__(16) short As[2][128 * 64];
  __shared__ __align__(16) short Bs[2][64 * 64];

  int bid  = blockIdx.x;
  int tile = bid & 31;
  int img  = bid >> 5;
  int m0 = (tile >> 3) * 128;
  int n0 = (tile & 7) * 64;

  int t = threadIdx.x;
  int lane = t & 63;
  int w  = t >> 6;
  int wr = (w >> 1) * 64;
  int wc = (w & 1) * 32;
  int lrow = lane & 15;
  int lq   = lane >> 4;

  int sl_s = 0, kb_s = kblo_f(m0, scale0);
  stage_tile<128>(G + (scale0 + sl_s) * MAT + m0 * HW + (kb_s << 6), As[0], w, lane);
  stage_tile<64>(Ut + (sl_s * NIMG + img) * MAT + n0 * HW + (kb_s << 6), Bs[0], w, lane);
  if (++kb_s == kbhi_f(m0, scale0 + sl_s)) { ++sl_s; if (sl_s < NS) kb_s = kblo_f(m0, scale0 + sl_s); }
  __syncthreads();
  int cur = 0;

  float suml[4][2][4];
  #pragma unroll
  for (int mi = 0; mi < 4; ++mi)
    #pragma unroll
    for (int ni = 0; ni < 2; ++ni)
      #pragma unroll
      for (int r = 0; r < 4; ++r) suml[mi][ni][r] = 0.f;

  for (int sl = 0; sl < NS; ++sl) {
    f4v acc[4][2];
    #pragma unroll
    for (int mi = 0; mi < 4; ++mi)
      #pragma unroll
      for (int ni = 0; ni < 2; ++ni)
        #pragma unroll
        for (int r = 0; r < 4; ++r) acc[mi][ni][r] = 0.f;

    int klo = kblo_f(m0, scale0 + sl), khi = kbhi_f(m0, scale0 + sl);
    for (int kb = klo; kb < khi; ++kb) {
      if (sl_s < NS) {
        stage_tile<128>(G + (scale0 + sl_s) * MAT + m0 * HW + (kb_s << 6), As[cur ^ 1], w, lane);
        stage_tile<64>(Ut + (sl_s * NIMG + img) * MAT + n0 * HW + (kb_s << 6), Bs[cur ^ 1], w, lane);
        if (++kb_s == kbhi_f(m0, scale0 + sl_s)) { ++sl_s; if (sl_s < NS) kb_s = kblo_f(m0, scale0 + sl_s); }
      }
      compute_bk64(As[cur], Bs[cur], wr, wc, lrow, lq, acc);
      __syncthreads();
      cur ^= 1;
    }

    #pragma unroll
    for (int mi = 0; mi < 4; ++mi)
      #pragma unroll
      for (int ni = 0; ni < 2; ++ni)
        #pragma unroll
        for (int r = 0; r < 4; ++r)
          suml[mi][ni][r] += fast_log1p(acc[mi][ni][r]);
  }

  const unsigned short* xb = Xb + img * MAT;
  float* O = out + img * MAT;
  #pragma unroll
  for (int mi = 0; mi < 4; ++mi)
    #pragma unroll
    for (int r = 0; r < 4; ++r) {
      int m = m0 + wr + mi * 16 + lq * 4 + r;
      #pragma unroll
      for (int ni = 0; ni < 2; ++ni) {
        int n = n0 + wc + ni * 16 + lrow;
        int idx = m * HW + n;
        if (ACCUM) {
          O[idx] = O[idx] - suml[mi][ni][r] * (1.0f / 3.0f);
        } else {
          O[idx] = fast_log1p(bf2f(xb[idx])) - suml[mi][ni][r] * (1.0f / 3.0f);
        }
      }
    }
}

// ---------- host ----------
extern "C" void kernel_launch(void* const* d_in, const int* in_sizes, int n_in,
                              void* d_out, int out_size, void* d_ws, size_t ws_size,
                              hipStream_t stream) {
  (void)in_sizes; (void)n_in; (void)out_size;
  const float* x = (const float*)d_in[0];
  float* out = (float*)d_out;
  unsigned short* Gbuf = (unsigned short*)d_ws;

  static const int scales[3] = {15, 80, 250};
  float i2s[3], nrm[3];
  for (int si = 0; si < 3; ++si) {
    double s = (double)scales[si];
    double S = 0.0;
    for (int c = -2 * scales[si]; c <= 2 * scales[si]; ++c)
      S += exp(-(double)c * (double)c / (2.0 * s * s));
    i2s[si] = (float)(1.0 / (2.0 * s * s));
    nrm[si] = (float)(1.0 / S);
  }

  size_t need_main = (size_t)(3 + 3 * NIMG + NIMG) * MAT * 2;  // G + Ut(3 scales) + Xb
  if (ws_size >= need_main) {
    unsigned short* Ut = Gbuf + 3 * MAT;
    unsigned short* Xb = Ut + (size_t)3 * NIMG * MAT;
    prep_kernel<<<NG_BLOCKS + NX_BLOCKS, 256, 0, stream>>>(
        x, Gbuf, Xb, out, 0, i2s[0], i2s[1], i2s[2], nrm[0], nrm[1], nrm[2]);
    pass1_kernel<3><<<NIMG * 32, 256, 0, stream>>>(Gbuf, Xb, Ut, 0);
    pass2_kernel<3, 0><<<NIMG * 32, 256, 0, stream>>>(Gbuf, Ut, Xb, out, 0);
  } else {
    // fallback: per-scale, Ut holds one scale (G + Ut(1) + Xb = 26.7MB)
    unsigned short* Ut = Gbuf + 3 * MAT;
    unsigned short* Xb = Ut + (size_t)NIMG * MAT;
    prep_kernel<<<NG_BLOCKS + NX_BLOCKS, 256, 0, stream>>>(
        x, Gbuf, Xb, out, 1, i2s[0], i2s[1], i2s[2], nrm[0], nrm[1], nrm[2]);
    for (int s = 0; s < 3; ++s) {
      pass1_kernel<1><<<NIMG * 32, 256, 0, stream>>>(Gbuf, Xb, Ut, s);
      pass2_kernel<1, 1><<<NIMG * 32, 256, 0, stream>>>(Gbuf, Ut, Xb, out, s);
    }
  }
}